// Round 1
// baseline (1314.380 us; speedup 1.0000x reference)
//
#include <hip/hip_runtime.h>
#include <hip/hip_bf16.h>
#include <cstdint>

#define VOCAB 32000
#define EMB   1024
#define TLEN  2048
#define NB    4
#define MTOT  (NB*TLEN)   // 8192 tokens

typedef __bf16 bf16;
typedef __bf16 bf16x8 __attribute__((ext_vector_type(8)));
typedef float  f32x4  __attribute__((ext_vector_type(4)));

// ---------------------------------------------------------------- embed ----
// x[r][c] = bf16( tok_emb[idx[r]][c] + pos_emb[r % T][c] ), 8 elems/thread
__global__ void embed_kernel(const int* __restrict__ idx,
                             const float* __restrict__ tok,
                             const float* __restrict__ pos,
                             bf16* __restrict__ x)
{
    int gid = blockIdx.x * 256 + threadIdx.x;   // 0 .. 8192*128-1
    int r   = gid >> 7;
    int c0  = (gid & 127) << 3;
    int t   = r & (TLEN - 1);
    int tk  = idx[r];
    const float4* tp = reinterpret_cast<const float4*>(tok + (long)tk * EMB + c0);
    const float4* pp = reinterpret_cast<const float4*>(pos + (long)t  * EMB + c0);
    float4 a0 = tp[0], a1 = tp[1];
    float4 b0 = pp[0], b1 = pp[1];
    bf16x8 o;
    o[0] = (bf16)(a0.x + b0.x); o[1] = (bf16)(a0.y + b0.y);
    o[2] = (bf16)(a0.z + b0.z); o[3] = (bf16)(a0.w + b0.w);
    o[4] = (bf16)(a1.x + b1.x); o[5] = (bf16)(a1.y + b1.y);
    o[6] = (bf16)(a1.z + b1.z); o[7] = (bf16)(a1.w + b1.w);
    *reinterpret_cast<bf16x8*>(x + (long)r * EMB + c0) = o;
}

// ------------------------------------------------- transpose + f32->bf16 ---
// W[K][N] f32  ->  Wt[N][K] bf16.   64x64 tile per block, 256 threads.
__global__ void transpose_conv_kernel(const float* __restrict__ W,
                                      bf16* __restrict__ Wt,
                                      int Kdim, int Ndim)
{
    __shared__ bf16 tile[64][65];
    int n0 = blockIdx.x * 64;
    int k0 = blockIdx.y * 64;
    int tid = threadIdx.x;
    int c  = tid & 63, r0 = tid >> 6;
#pragma unroll
    for (int i = 0; i < 16; ++i) {
        int r = r0 + i * 4;
        tile[r][c] = (bf16)W[(long)(k0 + r) * Ndim + n0 + c];
    }
    __syncthreads();
    int kc = tid & 63, nr0 = tid >> 6;
#pragma unroll
    for (int i = 0; i < 16; ++i) {
        int nr = nr0 + i * 4;
        Wt[(long)(n0 + nr) * Kdim + k0 + kc] = tile[kc][nr];
    }
}

// ---------------------------------------------------------------- GEMM -----
// C[M x N] = A[M x K] * Bt[N x K]^T   (both operands bf16, row-major, f32 acc)
// 128x128 tile, BK=32, 4 waves (2x2), each wave 64x64 via 4x4 16x16x32 MFMA.
// OMODE: 0 = store bf16, 1 = store f32, 2 = store f32 + bias[col]
__device__ __forceinline__ void gll16(const void* g, void* l)
{
    __builtin_amdgcn_global_load_lds(
        (const __attribute__((address_space(1))) unsigned int*)g,
        (__attribute__((address_space(3))) unsigned int*)l, 16, 0, 0);
}

template<int OMODE>
__global__ __launch_bounds__(256)
void gemm_bt_kernel(const bf16* __restrict__ A, int lda, long sA,
                    const bf16* __restrict__ Bt, int ldb, long sB,
                    void* __restrict__ Cv, int ldc, long sC,
                    int K, const float* __restrict__ bias)
{
    __shared__ bf16 As[128 * 32];
    __shared__ bf16 Bs[128 * 32];

    const int tid  = threadIdx.x;
    const int lane = tid & 63;
    const int wv   = tid >> 6;
    const int wr   = wv >> 1, wc = wv & 1;
    const long zb  = blockIdx.z;

    const bf16* Ab = A  + zb * sA + (long)(blockIdx.y * 128) * lda;
    const bf16* Bb = Bt + zb * sB + (long)(blockIdx.x * 128) * ldb;

    f32x4 acc[4][4] = {};

    // staging: lin = p*256 + tid; row = lin>>2, k-offset = (lin&3)*8; LDS byte = lin*16
    const int l0 = tid, l1 = tid + 256;
    const int r0s = l0 >> 2, kg0 = (l0 & 3) * 8;
    const int r1s = l1 >> 2, kg1 = (l1 & 3) * 8;

    for (int kt = 0; kt < K; kt += 32) {
        if (kt) __syncthreads();
        gll16(Ab + (long)r0s * lda + kt + kg0, &As[l0 * 8]);
        gll16(Ab + (long)r1s * lda + kt + kg1, &As[l1 * 8]);
        gll16(Bb + (long)r0s * ldb + kt + kg0, &Bs[l0 * 8]);
        gll16(Bb + (long)r1s * ldb + kt + kg1, &Bs[l1 * 8]);
        __syncthreads();

        bf16x8 af[4], bfr[4];
#pragma unroll
        for (int i = 0; i < 4; ++i) {
            af[i]  = *reinterpret_cast<const bf16x8*>(
                         &As[(wr * 64 + i * 16 + (lane & 15)) * 32 + (lane >> 4) * 8]);
            bfr[i] = *reinterpret_cast<const bf16x8*>(
                         &Bs[(wc * 64 + i * 16 + (lane & 15)) * 32 + (lane >> 4) * 8]);
        }
#pragma unroll
        for (int i = 0; i < 4; ++i)
#pragma unroll
            for (int j = 0; j < 4; ++j)
                acc[i][j] = __builtin_amdgcn_mfma_f32_16x16x32_bf16(
                                af[i], bfr[j], acc[i][j], 0, 0, 0);
    }

    // epilogue: C row = (lane>>4)*4 + reg, col = lane&15  (m89-verified layout)
    const int rowb = blockIdx.y * 128 + wr * 64 + ((lane >> 4) << 2);
    const int colb = blockIdx.x * 128 + wc * 64 + (lane & 15);

    if (OMODE == 0) {
        bf16* C = (bf16*)Cv + zb * sC;
#pragma unroll
        for (int i = 0; i < 4; ++i)
#pragma unroll
            for (int j = 0; j < 4; ++j)
#pragma unroll
                for (int r = 0; r < 4; ++r)
                    C[(long)(rowb + i * 16 + r) * ldc + colb + j * 16] = (bf16)acc[i][j][r];
    } else if (OMODE == 1) {
        float* C = (float*)Cv + zb * sC;
#pragma unroll
        for (int i = 0; i < 4; ++i)
#pragma unroll
            for (int j = 0; j < 4; ++j)
#pragma unroll
                for (int r = 0; r < 4; ++r)
                    C[(long)(rowb + i * 16 + r) * ldc + colb + j * 16] = acc[i][j][r];
    } else {
        float* C = (float*)Cv + zb * sC;
        float bv[4];
#pragma unroll
        for (int j = 0; j < 4; ++j) bv[j] = bias[colb + j * 16];
#pragma unroll
        for (int i = 0; i < 4; ++i)
#pragma unroll
            for (int j = 0; j < 4; ++j)
#pragma unroll
                for (int r = 0; r < 4; ++r)
                    C[(long)(rowb + i * 16 + r) * ldc + colb + j * 16] = acc[i][j][r] + bv[j];
    }
}

// ------------------------------------------------------ causal softmax -----
// one block per row r of S[8192][2048] (f32); writes P[8192][2048] bf16
__global__ void softmax_causal_kernel(const float* __restrict__ S,
                                      bf16* __restrict__ P)
{
    const int r = blockIdx.x;
    const int t = r & (TLEN - 1);
    const int tid = threadIdx.x;
    const int lane = tid & 63, wv = tid >> 6;
    const float scale = 0.03125f;             // 1024^-0.5
    const float* Sr = S + (long)r * TLEN;
    bf16* Pr = P + (long)r * TLEN;

    float v[8];
    float m = -1e30f;
#pragma unroll
    for (int i = 0; i < 8; ++i) {
        int c = tid + i * 256;
        float x = (c <= t) ? Sr[c] * scale : -1e30f;
        v[i] = x;
        m = fmaxf(m, x);
    }
    __shared__ float red[4];
#pragma unroll
    for (int off = 32; off; off >>= 1) m = fmaxf(m, __shfl_xor(m, off));
    if (lane == 0) red[wv] = m;
    __syncthreads();
    m = fmaxf(fmaxf(red[0], red[1]), fmaxf(red[2], red[3]));
    __syncthreads();

    float s = 0.f;
#pragma unroll
    for (int i = 0; i < 8; ++i) { v[i] = __expf(v[i] - m); s += v[i]; }
#pragma unroll
    for (int off = 32; off; off >>= 1) s += __shfl_xor(s, off);
    if (lane == 0) red[wv] = s;
    __syncthreads();
    s = red[0] + red[1] + red[2] + red[3];
    float inv = 1.0f / s;
#pragma unroll
    for (int i = 0; i < 8; ++i) {
        int c = tid + i * 256;
        Pr[c] = (bf16)(v[i] * inv);
    }
}

// ------------------------------------------------------------- loss --------
// per row: online logsumexp over 32000 logits; loss_r = lse - logit[tgt]
__global__ void loss_row_kernel(const float* __restrict__ logits,
                                const int* __restrict__ tgt,
                                float* __restrict__ rloss)
{
    const int r = blockIdx.x;
    const int tid = threadIdx.x;
    const int lane = tid & 63, wv = tid >> 6;
    const float* L = logits + (long)r * VOCAB;
    const float4* L4 = reinterpret_cast<const float4*>(L);

    float m = -1e30f, s = 0.f;
    for (int i = tid; i < VOCAB / 4; i += 256) {
        float4 x4 = L4[i];
        float xs[4] = {x4.x, x4.y, x4.z, x4.w};
#pragma unroll
        for (int q = 0; q < 4; ++q) {
            float x = xs[q];
            if (x <= m) s += __expf(x - m);
            else { s = s * __expf(m - x) + 1.0f; m = x; }
        }
    }
#pragma unroll
    for (int off = 32; off; off >>= 1) {
        float m2 = __shfl_xor(m, off);
        float s2 = __shfl_xor(s, off);
        float M = fmaxf(m, m2);
        s = s * __expf(m - M) + s2 * __expf(m2 - M);
        m = M;
    }
    __shared__ float rm[4], rs[4];
    if (lane == 0) { rm[wv] = m; rs[wv] = s; }
    __syncthreads();
    if (tid == 0) {
        float M = fmaxf(fmaxf(rm[0], rm[1]), fmaxf(rm[2], rm[3]));
        float S = rs[0] * __expf(rm[0] - M) + rs[1] * __expf(rm[1] - M) +
                  rs[2] * __expf(rm[2] - M) + rs[3] * __expf(rm[3] - M);
        float lse = M + __logf(S);
        rloss[r] = lse - L[tgt[r]];
    }
}

__global__ void loss_final_kernel(const float* __restrict__ rloss,
                                  float* __restrict__ out)
{
    const int tid = threadIdx.x;
    const int lane = tid & 63, wv = tid >> 6;
    float s = 0.f;
    for (int i = tid; i < MTOT; i += 256) s += rloss[i];
#pragma unroll
    for (int off = 32; off; off >>= 1) s += __shfl_xor(s, off);
    __shared__ float red[4];
    if (lane == 0) red[wv] = s;
    __syncthreads();
    if (tid == 0) out[0] = (red[0] + red[1] + red[2] + red[3]) * (1.0f / MTOT);
}

// ------------------------------------------------------------- launch ------
extern "C" void kernel_launch(void* const* d_in, const int* in_sizes, int n_in,
                              void* d_out, int out_size, void* d_ws, size_t ws_size,
                              hipStream_t stream)
{
    const int*   idx = (const int*)  d_in[0];
    const int*   tgt = (const int*)  d_in[1];
    const float* tok = (const float*)d_in[2];
    const float* pos = (const float*)d_in[3];
    const float* Wk  = (const float*)d_in[4];
    const float* Wq  = (const float*)d_in[5];
    const float* Wv  = (const float*)d_in[6];
    const float* Wlm = (const float*)d_in[7];
    const float* blm = (const float*)d_in[8];
    float* out = (float*)d_out;

    // workspace layout (bytes); aggressive aliasing, stream-order safe:
    //  [  0MB) x    bf16 16MB   | later: P bf16 32MB (x+q dead after S-GEMM)
    //  [ 16MB) q    bf16 16MB   |
    //  [ 32MB) k    bf16 16MB   | later: att bf16 16MB (k dead after S-GEMM)
    //  [ 48MB) v_t  bf16 16MB   | later: rloss f32    (v_t dead after PV)
    //  [ 64MB) S    f32  64MB   | later: Wlm_t bf16 62.5MB (S dead after softmax)
    //  [128MB) Wk_t, Wq_t, Wv_t bf16 2MB each  -> total 134MB
    char* ws = (char*)d_ws;
    if (ws_size < (size_t)140 * 1024 * 1024) return;  // refuse to corrupt memory

    bf16*  x     = (bf16*)(ws);
    bf16*  q     = (bf16*)(ws + (16l << 20));
    bf16*  k     = (bf16*)(ws + (32l << 20));
    bf16*  v_t   = (bf16*)(ws + (48l << 20));
    float* S     = (float*)(ws + (64l << 20));
    bf16*  Wk_t  = (bf16*)(ws + (128l << 20));
    bf16*  Wq_t  = (bf16*)(ws + (130l << 20));
    bf16*  Wv_t  = (bf16*)(ws + (132l << 20));
    // aliases
    bf16*  P     = (bf16*)(ws);                 // over x+q
    bf16*  att   = (bf16*)(ws + (32l << 20));   // over k
    float* rloss = (float*)(ws + (48l << 20));  // over v_t
    bf16*  Wlm_t = (bf16*)(ws + (64l << 20));   // over S

    // 1) embedding (f32 -> bf16)
    embed_kernel<<<dim3(MTOT * EMB / 8 / 256), 256, 0, stream>>>(idx, tok, pos, x);

    // 2) weight transposes to N x K bf16
    transpose_conv_kernel<<<dim3(16, 16), 256, 0, stream>>>(Wq, Wq_t, EMB, EMB);
    transpose_conv_kernel<<<dim3(16, 16), 256, 0, stream>>>(Wk, Wk_t, EMB, EMB);
    transpose_conv_kernel<<<dim3(16, 16), 256, 0, stream>>>(Wv, Wv_t, EMB, EMB);

    // 3) q = x @ Wq, k = x @ Wk (bf16 out); v_t[c][m] = Wv_t @ x^T
    gemm_bt_kernel<0><<<dim3(EMB / 128, MTOT / 128, 1), 256, 0, stream>>>(
        x, EMB, 0, Wq_t, EMB, 0, q, EMB, 0, EMB, nullptr);
    gemm_bt_kernel<0><<<dim3(EMB / 128, MTOT / 128, 1), 256, 0, stream>>>(
        x, EMB, 0, Wk_t, EMB, 0, k, EMB, 0, EMB, nullptr);
    gemm_bt_kernel<0><<<dim3(MTOT / 128, EMB / 128, 1), 256, 0, stream>>>(
        Wv_t, EMB, 0, x, EMB, 0, v_t, MTOT, 0, EMB, nullptr);

    // 4) S = q @ k^T (per batch, f32, unscaled)
    gemm_bt_kernel<1><<<dim3(TLEN / 128, TLEN / 128, NB), 256, 0, stream>>>(
        q, EMB, (long)TLEN * EMB, k, EMB, (long)TLEN * EMB,
        S, TLEN, (long)TLEN * TLEN, EMB, nullptr);

    // 5) P = softmax(causal(S * C^-0.5)) -> bf16
    softmax_causal_kernel<<<dim3(MTOT), 256, 0, stream>>>(S, P);

    // 6) Wlm transpose (into dead S buffer)
    transpose_conv_kernel<<<dim3(VOCAB / 64, EMB / 64), 256, 0, stream>>>(
        Wlm, Wlm_t, EMB, VOCAB);

    // 7) att = P @ v  (per batch; Bt = v_t slice, row stride MTOT, col offset b*T)
    gemm_bt_kernel<0><<<dim3(EMB / 128, TLEN / 128, NB), 256, 0, stream>>>(
        P, TLEN, (long)TLEN * TLEN, v_t, MTOT, (long)TLEN,
        att, EMB, (long)TLEN * EMB, TLEN, nullptr);

    // 8) logits = att @ Wlm + blm  (f32 straight to d_out)
    gemm_bt_kernel<2><<<dim3(VOCAB / 128, MTOT / 128, 1), 256, 0, stream>>>(
        att, EMB, 0, Wlm_t, EMB, 0, out, VOCAB, 0, EMB, blm);

    // 9) loss
    loss_row_kernel<<<dim3(MTOT), 256, 0, stream>>>(out, tgt, rloss);
    loss_final_kernel<<<1, 256, 0, stream>>>(rloss, out + (long)MTOT * VOCAB);
}

// Round 2
// 959.752 us; speedup vs baseline: 1.3695x; 1.3695x over previous
//
#include <hip/hip_runtime.h>
#include <hip/hip_bf16.h>
#include <cstdint>

#define VOCAB 32000
#define EMB   1024
#define TLEN  2048
#define NB    4
#define MTOT  (NB*TLEN)   // 8192 tokens

typedef __bf16 bf16;
typedef __bf16 bf16x8 __attribute__((ext_vector_type(8)));
typedef float  f32x4  __attribute__((ext_vector_type(4)));

// ---------------------------------------------------------------- embed ----
__global__ void embed_kernel(const int* __restrict__ idx,
                             const float* __restrict__ tok,
                             const float* __restrict__ pos,
                             bf16* __restrict__ x)
{
    int gid = blockIdx.x * 256 + threadIdx.x;
    int r   = gid >> 7;
    int c0  = (gid & 127) << 3;
    int t   = r & (TLEN - 1);
    int tk  = idx[r];
    const float4* tp = reinterpret_cast<const float4*>(tok + (long)tk * EMB + c0);
    const float4* pp = reinterpret_cast<const float4*>(pos + (long)t  * EMB + c0);
    float4 a0 = tp[0], a1 = tp[1];
    float4 b0 = pp[0], b1 = pp[1];
    bf16x8 o;
    o[0] = (bf16)(a0.x + b0.x); o[1] = (bf16)(a0.y + b0.y);
    o[2] = (bf16)(a0.z + b0.z); o[3] = (bf16)(a0.w + b0.w);
    o[4] = (bf16)(a1.x + b1.x); o[5] = (bf16)(a1.y + b1.y);
    o[6] = (bf16)(a1.z + b1.z); o[7] = (bf16)(a1.w + b1.w);
    *reinterpret_cast<bf16x8*>(x + (long)r * EMB + c0) = o;
}

// ------------------------------------------------- transpose + f32->bf16 ---
__global__ void transpose_conv_kernel(const float* __restrict__ W,
                                      bf16* __restrict__ Wt,
                                      int Kdim, int Ndim)
{
    __shared__ bf16 tile[64][65];
    int n0 = blockIdx.x * 64;
    int k0 = blockIdx.y * 64;
    int tid = threadIdx.x;
    int c  = tid & 63, r0 = tid >> 6;
#pragma unroll
    for (int i = 0; i < 16; ++i) {
        int r = r0 + i * 4;
        tile[r][c] = (bf16)W[(long)(k0 + r) * Ndim + n0 + c];
    }
    __syncthreads();
    int kc = tid & 63, nr0 = tid >> 6;
#pragma unroll
    for (int i = 0; i < 16; ++i) {
        int nr = nr0 + i * 4;
        Wt[(long)(n0 + nr) * Kdim + k0 + kc] = tile[kc][nr];
    }
}

// ------------------------------------------------------------- gll --------
__device__ __forceinline__ void gll16(const void* g, void* l)
{
    __builtin_amdgcn_global_load_lds(
        (const __attribute__((address_space(1))) unsigned int*)g,
        (__attribute__((address_space(3))) unsigned int*)l, 16, 0, 0);
}

// ------------------------------------------------- m97-style 128^2 GEMM ----
// C[M x N] = A[M x K] * Bt[N x K]^T, bf16 in, OMODE: 0 bf16 out, 1 f32 out
template<int OMODE>
__global__ __launch_bounds__(256)
void gemm_bt_kernel(const bf16* __restrict__ A, int lda, long sA,
                    const bf16* __restrict__ Bt, int ldb, long sB,
                    void* __restrict__ Cv, int ldc, long sC,
                    int K, const float* __restrict__ bias)
{
    __shared__ bf16 As[128 * 32];
    __shared__ bf16 Bs[128 * 32];

    const int tid  = threadIdx.x;
    const int lane = tid & 63;
    const int wv   = tid >> 6;
    const int wr   = wv >> 1, wc = wv & 1;
    const long zb  = blockIdx.z;

    const bf16* Ab = A  + zb * sA + (long)(blockIdx.y * 128) * lda;
    const bf16* Bb = Bt + zb * sB + (long)(blockIdx.x * 128) * ldb;

    f32x4 acc[4][4] = {};

    const int l0 = tid, l1 = tid + 256;
    const int r0s = l0 >> 2, kg0 = (l0 & 3) * 8;
    const int r1s = l1 >> 2, kg1 = (l1 & 3) * 8;

    for (int kt = 0; kt < K; kt += 32) {
        if (kt) __syncthreads();
        gll16(Ab + (long)r0s * lda + kt + kg0, &As[l0 * 8]);
        gll16(Ab + (long)r1s * lda + kt + kg1, &As[l1 * 8]);
        gll16(Bb + (long)r0s * ldb + kt + kg0, &Bs[l0 * 8]);
        gll16(Bb + (long)r1s * ldb + kt + kg1, &Bs[l1 * 8]);
        __syncthreads();

        bf16x8 af[4], bfr[4];
#pragma unroll
        for (int i = 0; i < 4; ++i) {
            af[i]  = *reinterpret_cast<const bf16x8*>(
                         &As[(wr * 64 + i * 16 + (lane & 15)) * 32 + (lane >> 4) * 8]);
            bfr[i] = *reinterpret_cast<const bf16x8*>(
                         &Bs[(wc * 64 + i * 16 + (lane & 15)) * 32 + (lane >> 4) * 8]);
        }
#pragma unroll
        for (int i = 0; i < 4; ++i)
#pragma unroll
            for (int j = 0; j < 4; ++j)
                acc[i][j] = __builtin_amdgcn_mfma_f32_16x16x32_bf16(
                                af[i], bfr[j], acc[i][j], 0, 0, 0);
    }

    const int rowb = blockIdx.y * 128 + wr * 64 + ((lane >> 4) << 2);
    const int colb = blockIdx.x * 128 + wc * 64 + (lane & 15);

    if (OMODE == 0) {
        bf16* C = (bf16*)Cv + zb * sC;
#pragma unroll
        for (int i = 0; i < 4; ++i)
#pragma unroll
            for (int j = 0; j < 4; ++j)
#pragma unroll
                for (int r = 0; r < 4; ++r)
                    C[(long)(rowb + i * 16 + r) * ldc + colb + j * 16] = (bf16)acc[i][j][r];
    } else {
        float* C = (float*)Cv + zb * sC;
#pragma unroll
        for (int i = 0; i < 4; ++i)
#pragma unroll
            for (int j = 0; j < 4; ++j)
#pragma unroll
                for (int r = 0; r < 4; ++r)
                    C[(long)(rowb + i * 16 + r) * ldc + colb + j * 16] = acc[i][j][r];
    }
}

// ---------------------------------------------- 256^2 2-phase logits GEMM --
// A = att [8192][1024], Bt = Wlm_t [32000][1024], C = logits f32 [8192][32000]
// + bias, + fused per-(row, colblock) logsumexp partials.
// 512 thr = 8 waves (2M x 4N); per-wave 128x64; BK=64; LDS 128 KiB dyn dbuf.
// LDS swizzle: byte-in-row ^= (row&7)<<4 (G4 fix); gll source pre-swizzled.
__device__ __forceinline__ void stage256(const bf16* __restrict__ gbase, int kt,
                                         bf16* lbase, int tid)
{
#pragma unroll
    for (int p = 0; p < 4; ++p) {
        int lin  = p * 512 + tid;
        int row  = lin >> 3;
        int slot = lin & 7;
        int ke   = ((slot ^ (row & 7)) << 3) + kt;
        gll16(gbase + (long)row * EMB + ke, lbase + lin * 8);
    }
}

__global__ __launch_bounds__(512)
void gemm256_logits(const bf16* __restrict__ A, const bf16* __restrict__ Bt,
                    float* __restrict__ C, const float* __restrict__ bias,
                    float2* __restrict__ part)
{
    extern __shared__ bf16 smem[];          // 131072 B
    bf16* As = smem;                        // [2][256*64]
    bf16* Bs = smem + 32768;

    const int tid  = threadIdx.x;
    const int lane = tid & 63, wid = tid >> 6;
    const int wr = wid >> 2, wc = wid & 3;
    const int l15 = lane & 15, hi = lane >> 4, l7 = lane & 7;

    // bijective XCD swizzle: 4000 wgs = 8 XCDs x 500; nb outer, mb(4) inner
    const int wg = blockIdx.x;
    const int xcd = wg & 7, c = wg >> 3;      // c in [0,500)
    const int nb = c >> 2;                    // [0,125)
    const int mb = xcd * 4 + (c & 3);         // [0,32)

    const bf16* Ab = A  + (long)(mb * 256) * EMB;
    const bf16* Bb = Bt + (long)(nb * 256) * EMB;

    f32x4 acc[8][4] = {};

    stage256(Ab, 0, As, tid);
    stage256(Bb, 0, Bs, tid);
    __syncthreads();

    const int NT = EMB / 64;                  // 16
    for (int t = 0; t < NT; ++t) {
        const int buf = t & 1;
        if (t + 1 < NT) {
            stage256(Ab, (t + 1) * 64, As + (buf ^ 1) * 16384, tid);
            stage256(Bb, (t + 1) * 64, Bs + (buf ^ 1) * 16384, tid);
        }
        const bf16* Ap = As + buf * 16384 + (wr * 128) * 64;
        const bf16* Bp = Bs + buf * 16384 + (wc * 64) * 64;
#pragma unroll
        for (int ks = 0; ks < 2; ++ks) {
            const int ko = 8 * (((ks << 2) | hi) ^ l7);   // swizzled k-offset
            bf16x8 bfr[4];
#pragma unroll
            for (int n = 0; n < 4; ++n)
                bfr[n] = *(const bf16x8*)(Bp + (n * 16 + l15) * 64 + ko);
#pragma unroll
            for (int m = 0; m < 8; ++m) {
                bf16x8 af = *(const bf16x8*)(Ap + (m * 16 + l15) * 64 + ko);
#pragma unroll
                for (int n = 0; n < 4; ++n)
                    acc[m][n] = __builtin_amdgcn_mfma_f32_16x16x32_bf16(
                                    af, bfr[n], acc[m][n], 0, 0, 0);
            }
        }
        __syncthreads();   // drains vmcnt (retires stage t+1) + frees buf
    }

    // ---- epilogue: bias + store f32 + fused row-partial logsumexp ----
    float* pm = (float*)smem;                 // [4][256]
    float* ps = pm + 1024;                    // [4][256]

    const long colbase = (long)nb * 256 + wc * 64 + l15;
    float bv[4];
#pragma unroll
    for (int n = 0; n < 4; ++n) bv[n] = bias[colbase + n * 16];

    const long rowbase = (long)mb * 256 + wr * 128;
#pragma unroll
    for (int m = 0; m < 8; ++m) {
#pragma unroll
        for (int r = 0; r < 4; ++r) {
            float v0 = acc[m][0][r] + bv[0];
            float v1 = acc[m][1][r] + bv[1];
            float v2 = acc[m][2][r] + bv[2];
            float v3 = acc[m][3][r] + bv[3];
            long row = rowbase + m * 16 + (hi << 2) + r;
            float* Cp = C + row * (long)VOCAB + colbase;
            Cp[0] = v0; Cp[16] = v1; Cp[32] = v2; Cp[48] = v3;

            float lm = fmaxf(fmaxf(v0, v1), fmaxf(v2, v3));
#pragma unroll
            for (int o = 1; o < 16; o <<= 1) lm = fmaxf(lm, __shfl_xor(lm, o));
            float sp = __expf(v0 - lm) + __expf(v1 - lm) +
                       __expf(v2 - lm) + __expf(v3 - lm);
#pragma unroll
            for (int o = 1; o < 16; o <<= 1) sp += __shfl_xor(sp, o);
            if (l15 == 0) {
                int rb = wr * 128 + m * 16 + (hi << 2) + r;
                pm[wc * 256 + rb] = lm;
                ps[wc * 256 + rb] = sp;
            }
        }
    }
    __syncthreads();
    if (tid < 256) {
        float m0 = pm[tid], m1 = pm[256 + tid], m2 = pm[512 + tid], m3 = pm[768 + tid];
        float M = fmaxf(fmaxf(m0, m1), fmaxf(m2, m3));
        float S = ps[tid] * __expf(m0 - M) + ps[256 + tid] * __expf(m1 - M) +
                  ps[512 + tid] * __expf(m2 - M) + ps[768 + tid] * __expf(m3 - M);
        part[((long)mb * 256 + tid) * 125 + nb] = make_float2(M, S);
    }
}

// ------------------------------------------------------ causal softmax -----
// S bf16 [8192][2048] -> P bf16; one block per row, 8 contiguous cols/thread
__global__ void softmax_causal_kernel(const bf16* __restrict__ S,
                                      bf16* __restrict__ P)
{
    const int r = blockIdx.x;
    const int t = r & (TLEN - 1);
    const int tid = threadIdx.x;
    const int lane = tid & 63, wv = tid >> 6;
    const float scale = 0.03125f;
    const int c0 = tid * 8;
    bf16x8 sv = *(const bf16x8*)(S + (long)r * TLEN + c0);

    float v[8];
    float m = -1e30f;
#pragma unroll
    for (int i = 0; i < 8; ++i) {
        float x = (c0 + i <= t) ? (float)sv[i] * scale : -1e30f;
        v[i] = x;
        m = fmaxf(m, x);
    }
    __shared__ float red[4];
#pragma unroll
    for (int off = 32; off; off >>= 1) m = fmaxf(m, __shfl_xor(m, off));
    if (lane == 0) red[wv] = m;
    __syncthreads();
    m = fmaxf(fmaxf(red[0], red[1]), fmaxf(red[2], red[3]));
    __syncthreads();

    float s = 0.f;
#pragma unroll
    for (int i = 0; i < 8; ++i) { v[i] = __expf(v[i] - m); s += v[i]; }
#pragma unroll
    for (int off = 32; off; off >>= 1) s += __shfl_xor(s, off);
    if (lane == 0) red[wv] = s;
    __syncthreads();
    s = red[0] + red[1] + red[2] + red[3];
    float inv = 1.0f / s;
    bf16x8 o;
#pragma unroll
    for (int i = 0; i < 8; ++i) o[i] = (bf16)(v[i] * inv);
    *(bf16x8*)(P + (long)r * TLEN + c0) = o;
}

// ------------------------------------------------------------- loss --------
// merge 125 (m,s) partials per row; loss_r = lse - logit[tgt]
__global__ void loss_combine_kernel(const float2* __restrict__ part,
                                    const float* __restrict__ logits,
                                    const int* __restrict__ tgt,
                                    float* __restrict__ bsum)
{
    const int tid = threadIdx.x;
    const int row = blockIdx.x * 256 + tid;
    const int lane = tid & 63, wv = tid >> 6;
    const float2* p = part + (long)row * 125;
    float M = -1e30f, S = 0.f;
    for (int i = 0; i < 125; ++i) {
        float2 v = p[i];
        if (v.x <= M) S += v.y * __expf(v.x - M);
        else { S = S * __expf(M - v.x) + v.y; M = v.x; }
    }
    float lse = M + __logf(S);
    float l = lse - logits[(long)row * VOCAB + tgt[row]];
#pragma unroll
    for (int off = 32; off; off >>= 1) l += __shfl_xor(l, off);
    __shared__ float red[4];
    if (lane == 0) red[wv] = l;
    __syncthreads();
    if (tid == 0) bsum[blockIdx.x] = red[0] + red[1] + red[2] + red[3];
}

__global__ void loss_final_kernel(const float* __restrict__ bsum,
                                  float* __restrict__ out)
{
    const int lane = threadIdx.x;
    float s = (lane < 32) ? bsum[lane] : 0.f;
#pragma unroll
    for (int off = 32; off; off >>= 1) s += __shfl_xor(s, off);
    if (lane == 0) out[0] = s * (1.0f / MTOT);
}

// ------------------------------------------------------------- launch ------
extern "C" void kernel_launch(void* const* d_in, const int* in_sizes, int n_in,
                              void* d_out, int out_size, void* d_ws, size_t ws_size,
                              hipStream_t stream)
{
    const int*   idx = (const int*)  d_in[0];
    const int*   tgt = (const int*)  d_in[1];
    const float* tok = (const float*)d_in[2];
    const float* pos = (const float*)d_in[3];
    const float* Wk  = (const float*)d_in[4];
    const float* Wq  = (const float*)d_in[5];
    const float* Wv  = (const float*)d_in[6];
    const float* Wlm = (const float*)d_in[7];
    const float* blm = (const float*)d_in[8];
    float* out = (float*)d_out;

    // ws layout (MB, stream-order-safe aliasing):
    //  [  0, 16) x bf16            -> att bf16 (x dead after v_t/qk GEMMs)
    //  [ 16, 48) qk bf16 [8192][2048] -> P bf16 (qk dead after S GEMM)
    //  [ 48, 64) v_t bf16          \
    //  [ 64, 96) S bf16             > Wlm_t [48,110.5) after PV
    //  [ 96,100) Wqk_t bf16        /
    //  [100,102) Wv_t bf16        /
    //  [112,120) loss partials float2 [8192][125]
    //  [120,..)  bsum f32 [32]
    char* ws = (char*)d_ws;
    if (ws_size < (size_t)140 * 1024 * 1024) return;

    bf16*   x     = (bf16*)(ws);
    bf16*   qk    = (bf16*)(ws + (16l << 20));
    bf16*   v_t   = (bf16*)(ws + (48l << 20));
    bf16*   S     = (bf16*)(ws + (64l << 20));
    bf16*   Wqk_t = (bf16*)(ws + (96l << 20));
    bf16*   Wv_t  = (bf16*)(ws + (100l << 20));
    bf16*   att   = (bf16*)(ws);                  // over x
    bf16*   P     = (bf16*)(ws + (16l << 20));    // over qk
    bf16*   Wlm_t = (bf16*)(ws + (48l << 20));    // over v_t+S+W*_t after PV
    float2* part  = (float2*)(ws + (112l << 20));
    float*  bsum  = (float*)(ws + (120l << 20));

    // 1) embedding
    embed_kernel<<<dim3(MTOT * EMB / 8 / 256), 256, 0, stream>>>(idx, tok, pos, x);

    // 2) weight transposes (Wq|Wk stacked into one [2048][1024] operand)
    transpose_conv_kernel<<<dim3(16, 16), 256, 0, stream>>>(Wq, Wqk_t, EMB, EMB);
    transpose_conv_kernel<<<dim3(16, 16), 256, 0, stream>>>(Wk, Wqk_t + 1024 * 1024, EMB, EMB);
    transpose_conv_kernel<<<dim3(16, 16), 256, 0, stream>>>(Wv, Wv_t, EMB, EMB);

    // 3) qk = x @ [Wq|Wk]  (one GEMM, N=2048);  v_t = Wv_t @ x^T
    gemm_bt_kernel<0><<<dim3(2048 / 128, MTOT / 128, 1), 256, 0, stream>>>(
        x, EMB, 0, Wqk_t, EMB, 0, qk, 2048, 0, EMB, nullptr);
    gemm_bt_kernel<0><<<dim3(MTOT / 128, EMB / 128, 1), 256, 0, stream>>>(
        Wv_t, EMB, 0, x, EMB, 0, v_t, MTOT, 0, EMB, nullptr);

    // 4) S = q @ k^T (per batch, bf16 out, unscaled)
    gemm_bt_kernel<0><<<dim3(TLEN / 128, TLEN / 128, NB), 256, 0, stream>>>(
        qk, 2048, (long)TLEN * 2048, qk + 1024, 2048, (long)TLEN * 2048,
        S, TLEN, (long)TLEN * TLEN, EMB, nullptr);

    // 5) P = softmax(causal(S * C^-0.5))
    softmax_causal_kernel<<<dim3(MTOT), 256, 0, stream>>>(S, P);

    // 6) att = P @ v
    gemm_bt_kernel<0><<<dim3(EMB / 128, TLEN / 128, NB), 256, 0, stream>>>(
        P, TLEN, (long)TLEN * TLEN, v_t, MTOT, (long)TLEN,
        att, EMB, (long)TLEN * EMB, TLEN, nullptr);

    // 7) Wlm transpose (into region freed by v_t/S/W*_t)
    transpose_conv_kernel<<<dim3(VOCAB / 64, EMB / 64), 256, 0, stream>>>(
        Wlm, Wlm_t, EMB, VOCAB);

    // 8) logits = att @ Wlm + blm, fused loss partials
    gemm256_logits<<<dim3(4000), 512, 131072, stream>>>(att, Wlm_t, out, blm, part);

    // 9) loss
    loss_combine_kernel<<<dim3(32), 256, 0, stream>>>(part, out, tgt, bsum);
    loss_final_kernel<<<dim3(1), 64, 0, stream>>>(bsum, out + (long)MTOT * VOCAB);
}